// Round 10
// baseline (482.324 us; speedup 1.0000x reference)
//
#include <hip/hip_runtime.h>
#include <math.h>

#define NN 100000
#define RR 4
#define EE 300000
#define PP 2
#define HH 64
#define SS 4096
#define NSEG (NN * RR)          // 400000 segments
#define FPART 8
#define PWIDTH ((NN + FPART - 1) / FPART)   // 12500

typedef __attribute__((ext_vector_type(8))) short short8;
typedef __attribute__((ext_vector_type(4))) short short4v;
typedef __attribute__((ext_vector_type(4))) float f32x4;
typedef __attribute__((ext_vector_type(2))) int int2v;

__device__ __forceinline__ short f2bf(float v) {
    unsigned u = __float_as_uint(v);
    unsigned r = (u + 0x7FFFu + ((u >> 16) & 1u)) >> 16;
    return (short)r;
}
__device__ __forceinline__ float bf2f(short s) {
    return __uint_as_float(((unsigned)(unsigned short)s) << 16);
}

// ---- consolidated prep: Wr both layers + dense weight transp/split + x->bf16 ----
struct PrepPtrs {
    const float *Wlin, *Wd1, *Wd2, *Wf1, *Wf2, *Wf3;
    short *Wlin_hi, *Wlin_lo, *Wd1_hi, *Wd1_lo, *Wd2_hi, *Wd2_lo,
          *Wf1_hi, *Wf1_lo, *Wf2_hi, *Wf2_lo, *Wf3_hi, *Wf3_lo;
    const float *C1, *V1, *C2, *V2;
    short *wr1_hi, *wr1_lo, *wr2_hi, *wr2_lo;
    const float *x;
    short *xb;
};

__device__ __forceinline__ void tsp_one(const float* __restrict__ W, short* __restrict__ hi,
                                        short* __restrict__ lo, int K, int N, int idx) {
    int total = K * N;
    int z = idx / total;
    int rem = idx - z * total;
    int n = rem / K;
    int k = rem - n * K;
    float v = W[(long long)z * total + (long long)k * N + n];
    short h = f2bf(v);
    hi[idx] = h;
    lo[idx] = f2bf(v - bf2f(h));
}

#define T0 4096
#define T1 32768
#define T2 16384
#define T3 32768
#define T4 1048576
#define T5 1310720
#define TSP_TOTAL (T0 + T1 + T2 + T3 + T4 + T5)   // 2445312 = 9552*256
#define WR_BLK 128
#define TSP_BLK 9552
#define XB_BLK 6250

__global__ void prep_all(PrepPtrs pp) {
    int b = blockIdx.x;
    if (b < WR_BLK) {
        const float* C = (b < 64) ? pp.C1 : pp.C2;
        const float* V = (b < 64) ? pp.V1 : pp.V2;
        short* hi = (b < 64) ? pp.wr1_hi : pp.wr2_hi;
        short* lo = (b < 64) ? pp.wr1_lo : pp.wr2_lo;
        int idx = (b & 63) * 256 + threadIdx.x;
        int o = idx >> 8;
        int ri = idx & 255;
        int r = ri >> 6;
        int i = ri & 63;
        float v = C[r * 2] * V[i * 64 + o] + C[r * 2 + 1] * V[4096 + i * 64 + o];
        short h = f2bf(v);
        hi[idx] = h;
        lo[idx] = f2bf(v - bf2f(h));
        return;
    }
    b -= WR_BLK;
    if (b < TSP_BLK) {
        int idx = b * 256 + threadIdx.x;
        if (idx < T0) { tsp_one(pp.Wlin, pp.Wlin_hi, pp.Wlin_lo, 64, 64, idx); return; }
        idx -= T0;
        if (idx < T1) { tsp_one(pp.Wd1, pp.Wd1_hi, pp.Wd1_lo, 64, 256, idx); return; }
        idx -= T1;
        if (idx < T2) { tsp_one(pp.Wd2, pp.Wd2_hi, pp.Wd2_lo, 256, 32, idx); return; }
        idx -= T2;
        if (idx < T3) { tsp_one(pp.Wf1, pp.Wf1_hi, pp.Wf1_lo, 64, 256, idx); return; }
        idx -= T3;
        if (idx < T4) { tsp_one(pp.Wf2, pp.Wf2_hi, pp.Wf2_lo, 256, 2048, idx); return; }
        idx -= T4;
        tsp_one(pp.Wf3, pp.Wf3_hi, pp.Wf3_lo, 2048, 320, idx);
        return;
    }
    b -= TSP_BLK;
    int idx = b * 256 + threadIdx.x;          // < 1,600,000 (NN*HH/4)
    f32x4 v = *(const f32x4*)&pp.x[(long long)idx * 4];
    short4v o;
    #pragma unroll
    for (int c = 0; c < 4; c++) o[c] = f2bf(v[c]);
    *(short4v*)&pp.xb[(long long)idx * 4] = o;
}

// ---------------- CSR build ----------------
// NT edge loads: edges are streamed once/8x; keep them OUT of L2 so the dirty
// counts/csr_src accumulation lines stay resident until full (fixes RMW thrash).
__global__ void count_kernel(const int* __restrict__ edges, int* __restrict__ counts) {
    int idx = blockIdx.x * 256 + threadIdx.x;
    if (idx >= RR * EE) return;
    int r = idx / EE;
    int2v e = __builtin_nontemporal_load((const int2v*)edges + idx);
    atomicAdd(&counts[e.y * RR + r], 1);
}

__global__ void scan1(const int* __restrict__ counts, int* __restrict__ excl,
                      int* __restrict__ bsums, int n) {
    __shared__ int tmp[256];
    int tid = threadIdx.x;
    int gid = blockIdx.x * 256 + tid;
    int v = (gid < n) ? counts[gid] : 0;
    tmp[tid] = v;
    __syncthreads();
    #pragma unroll
    for (int off = 1; off < 256; off <<= 1) {
        int y = (tid >= off) ? tmp[tid - off] : 0;
        __syncthreads();
        tmp[tid] += y;
        __syncthreads();
    }
    if (gid < n) excl[gid] = tmp[tid] - v;
    if (tid == 255) bsums[blockIdx.x] = tmp[255];
}

__global__ void scan2(int* __restrict__ bsums, int nb) {
    __shared__ int tmp[256];
    __shared__ int carry;
    int tid = threadIdx.x;
    if (tid == 0) carry = 0;
    __syncthreads();
    for (int base = 0; base < nb; base += 256) {
        int i = base + tid;
        int v = (i < nb) ? bsums[i] : 0;
        tmp[tid] = v;
        __syncthreads();
        #pragma unroll
        for (int off = 1; off < 256; off <<= 1) {
            int y = (tid >= off) ? tmp[tid - off] : 0;
            __syncthreads();
            tmp[tid] += y;
            __syncthreads();
        }
        if (i < nb) bsums[i] = tmp[tid] - v + carry;
        __syncthreads();
        if (tid == 0) carry += tmp[255];
        __syncthreads();
    }
}

__global__ void scan3(const int* __restrict__ excl, const int* __restrict__ bsums,
                      int* __restrict__ row_ptr, int* __restrict__ cursor, int n, int total) {
    int gid = blockIdx.x * 256 + threadIdx.x;
    if (gid < n) {
        int v = excl[gid] + bsums[gid >> 8];
        row_ptr[gid] = v;
        cursor[gid] = v;
    }
    if (gid == 0) row_ptr[n] = total;
}

// fill: dst-partitioned (part == XCD via blockIdx round-robin) + NT edge loads
__global__ void fill_csr(const int* __restrict__ edges, int* __restrict__ cursor,
                         int* __restrict__ csr_src) {
    int part = blockIdx.x & (FPART - 1);
    int idx = (blockIdx.x >> 3) * 256 + threadIdx.x;
    if (idx >= RR * EE) return;
    int2v e = __builtin_nontemporal_load((const int2v*)edges + idx);
    int dst = e.y;
    int lo = part * PWIDTH;
    if (dst < lo || dst >= lo + PWIDTH) return;
    int r = idx / EE;
    int pos = atomicAdd(&cursor[dst * RR + r], 1);
    csr_src[pos] = e.x;
}

// ---------------- gather aggregation ----------------
// One segment per 8-lane group; lane covers 8 channels via one 16B load.
// 4-wide batched independent loads; 8 segments per wave.
__global__ __launch_bounds__(256) void gather_agg(const int* __restrict__ row_ptr,
                                                  const int* __restrict__ csr_src,
                                                  const short* __restrict__ feat,
                                                  short* __restrict__ agg) {
    long long tg = (long long)blockIdx.x * 256 + threadIdx.x;
    long long seg = tg >> 3;
    int cl = threadIdx.x & 7;           // channels 8cl .. 8cl+7
    if (seg >= (long long)NSEG) return;
    int beg = row_ptr[seg];
    int end = row_ptr[seg + 1];
    float s[8] = {0.f, 0.f, 0.f, 0.f, 0.f, 0.f, 0.f, 0.f};
    int i = beg;
    for (; i + 4 <= end; i += 4) {
        int a = csr_src[i];
        int b = csr_src[i + 1];
        int c = csr_src[i + 2];
        int d = csr_src[i + 3];
        short8 va = *(const short8*)&feat[a * HH + cl * 8];
        short8 vb = *(const short8*)&feat[b * HH + cl * 8];
        short8 vc = *(const short8*)&feat[c * HH + cl * 8];
        short8 vd = *(const short8*)&feat[d * HH + cl * 8];
        #pragma unroll
        for (int j = 0; j < 8; j++)
            s[j] += (bf2f(va[j]) + bf2f(vb[j])) + (bf2f(vc[j]) + bf2f(vd[j]));
    }
    int rem = end - i;
    if (rem > 0) {
        int a = csr_src[i];
        int b = csr_src[rem > 1 ? i + 1 : i];
        int c = csr_src[rem > 2 ? i + 2 : i];
        short8 va = *(const short8*)&feat[a * HH + cl * 8];
        short8 vb = *(const short8*)&feat[b * HH + cl * 8];
        short8 vc = *(const short8*)&feat[c * HH + cl * 8];
        #pragma unroll
        for (int j = 0; j < 8; j++) {
            s[j] += bf2f(va[j]);
            s[j] += (rem > 1) ? bf2f(vb[j]) : 0.f;
            s[j] += (rem > 2) ? bf2f(vc[j]) : 0.f;
        }
    }
    int d = end - beg;
    float inv = 1.0f / (float)(d > 1 ? d : 1);
    short8 o;
    #pragma unroll
    for (int j = 0; j < 8; j++) o[j] = f2bf(s[j] * inv);
    *(short8*)&agg[seg * HH + cl * 8] = o;
}

// split-K reduction + bias + tanh for f3
__global__ void reduce_tanh(const float* __restrict__ part, const float* __restrict__ bf3,
                            float* __restrict__ out) {
    int idx = blockIdx.x * 256 + threadIdx.x;
    if (idx >= PP * SS * 320) return;
    int p = idx / (SS * 320);
    int rem = idx - p * (SS * 320);
    int n = rem % 320;
    float s = bf3[p * 320 + n];
    #pragma unroll
    for (int ks = 0; ks < 4; ks++)
        s += part[((long long)(p * 4 + ks)) * SS * 320 + rem];
    out[idx] = tanhf(s);
}

// ======== combine1: h1 = relu(agg @ Wr1), 64-row tile, grid 1563 ========
__global__ __launch_bounds__(256) void combine1_kernel(
    const short* __restrict__ A,                                   // [NN][256]
    const short* __restrict__ Bhi, const short* __restrict__ Blo,  // [64][256]
    short* __restrict__ h1)
{
    __shared__ short As[64 * 32];
    __shared__ short Bs_hi[64 * 32];
    __shared__ short Bs_lo[64 * 32];

    int tid = threadIdx.x;
    int lane = tid & 63;
    int w = tid >> 6, wm = w >> 1, wn = w & 1;
    int mrow = lane & 15, quad = lane >> 4;
    int m0 = blockIdx.x * 64;

    f32x4 acc[2][2];
    #pragma unroll
    for (int s = 0; s < 2; s++)
        #pragma unroll
        for (int t = 0; t < 2; t++)
            acc[s][t] = (f32x4){0.f, 0.f, 0.f, 0.f};

    for (int k0 = 0; k0 < 256; k0 += 32) {
        {
            int m = tid >> 2, q = tid & 3;
            int gm = m0 + m;
            short8 av = (short8)0;
            if (gm < NN) av = *(const short8*)&A[(long long)gm * 256 + k0 + q * 8];
            *(short8*)&As[m * 32 + q * 8] = av;
            long long boff = (long long)m * 256 + k0 + q * 8;   // m doubles as n
            *(short8*)&Bs_hi[m * 32 + q * 8] = *(const short8*)&Bhi[boff];
            *(short8*)&Bs_lo[m * 32 + q * 8] = *(const short8*)&Blo[boff];
        }
        __syncthreads();

        short8 ah[2], bh[2], bl[2];
        #pragma unroll
        for (int s = 0; s < 2; s++)
            ah[s] = *(const short8*)&As[(wm * 32 + s * 16 + mrow) * 32 + quad * 8];
        #pragma unroll
        for (int t = 0; t < 2; t++) {
            int soff = (wn * 32 + t * 16 + mrow) * 32 + quad * 8;
            bh[t] = *(const short8*)&Bs_hi[soff];
            bl[t] = *(const short8*)&Bs_lo[soff];
        }
        #pragma unroll
        for (int s = 0; s < 2; s++)
            #pragma unroll
            for (int t = 0; t < 2; t++) {
                acc[s][t] = __builtin_amdgcn_mfma_f32_16x16x32_bf16(ah[s], bh[t], acc[s][t], 0, 0, 0);
                acc[s][t] = __builtin_amdgcn_mfma_f32_16x16x32_bf16(ah[s], bl[t], acc[s][t], 0, 0, 0);
            }
        __syncthreads();
    }

    #pragma unroll
    for (int s = 0; s < 2; s++) {
        int gmBase = m0 + wm * 32 + s * 16 + quad * 4;
        #pragma unroll
        for (int t = 0; t < 2; t++) {
            int gn = wn * 32 + t * 16 + mrow;
            #pragma unroll
            for (int r = 0; r < 4; r++) {
                int gm = gmBase + r;
                if (gm >= NN) continue;
                h1[(long long)gm * 64 + gn] = f2bf(fmaxf(acc[s][t][r], 0.f));
            }
        }
    }
}

// ======== combine2+linear fused: h3b = bf16(leaky(relu(agg@Wr2) @ Wlin + blin) + noise) =
__global__ __launch_bounds__(256) void combine2_linear(
    const short* __restrict__ A,                                       // agg2 [NN][256]
    const short* __restrict__ Bhi, const short* __restrict__ Blo,      // Wr2t [64][256]
    const short* __restrict__ Lhi, const short* __restrict__ Llo,      // Wlint [64][64]
    const float* __restrict__ blin, const float* __restrict__ noise,
    short* __restrict__ h3b)
{
    __shared__ short smem[6144];       // As | Bs_hi | Bs_lo ; h2s (64x72) aliases all
    short* As = smem;
    short* Bs_hi = smem + 2048;
    short* Bs_lo = smem + 4096;
    short* h2s = smem;

    int tid = threadIdx.x;
    int lane = tid & 63;
    int w = tid >> 6, wm = w >> 1, wn = w & 1;
    int mrow = lane & 15, quad = lane >> 4;
    int m0 = blockIdx.x * 64;

    // Wlin fragments in registers (this wave's cols, both k-halves, hi+lo)
    short8 lhi[2][2], llo[2][2];
    #pragma unroll
    for (int t = 0; t < 2; t++)
        #pragma unroll
        for (int kk = 0; kk < 2; kk++) {
            int loff = (wn * 32 + t * 16 + mrow) * 64 + kk * 32 + quad * 8;
            lhi[t][kk] = *(const short8*)&Lhi[loff];
            llo[t][kk] = *(const short8*)&Llo[loff];
        }

    f32x4 acc[2][2];
    #pragma unroll
    for (int s = 0; s < 2; s++)
        #pragma unroll
        for (int t = 0; t < 2; t++)
            acc[s][t] = (f32x4){0.f, 0.f, 0.f, 0.f};

    for (int k0 = 0; k0 < 256; k0 += 32) {
        {
            int m = tid >> 2, q = tid & 3;
            int gm = m0 + m;
            short8 av = (short8)0;
            if (gm < NN) av = *(const short8*)&A[(long long)gm * 256 + k0 + q * 8];
            *(short8*)&As[m * 32 + q * 8] = av;
            long long boff = (long long)m * 256 + k0 + q * 8;
            *(short8*)&Bs_hi[m * 32 + q * 8] = *(const short8*)&Bhi[boff];
            *(short8*)&Bs_lo[m * 32 + q * 8] = *(const short8*)&Blo[boff];
        }
        __syncthreads();

        short8 ah[2], bh[2], bl[2];
        #pragma unroll
        for (int s = 0; s < 2; s++)
            ah[s] = *(const short8*)&As[(wm * 32 + s * 16 + mrow) * 32 + quad * 8];
        #pragma unroll
        for (int t = 0; t < 2; t++) {
            int soff = (wn * 32 + t * 16 + mrow) * 32 + quad * 8;
            bh[t] = *(const short8*)&Bs_hi[soff];
            bl[t] = *(const short8*)&Bs_lo[soff];
        }
        #pragma unroll
        for (int s = 0; s < 2; s++)
            #pragma unroll
            for (int t = 0; t < 2; t++) {
                acc[s][t] = __builtin_amdgcn_mfma_f32_16x16x32_bf16(ah[s], bh[t], acc[s][t], 0, 0, 0);
                acc[s][t] = __builtin_amdgcn_mfma_f32_16x16x32_bf16(ah[s], bl[t], acc[s][t], 0, 0, 0);
            }
        __syncthreads();
    }

    // h2 = relu(acc) -> aliased LDS (stride 72 to break bank conflicts)
    #pragma unroll
    for (int s = 0; s < 2; s++) {
        int rowB = wm * 32 + s * 16 + quad * 4;
        #pragma unroll
        for (int t = 0; t < 2; t++) {
            int col = wn * 32 + t * 16 + mrow;
            #pragma unroll
            for (int r = 0; r < 4; r++)
                h2s[(rowB + r) * 72 + col] = f2bf(fmaxf(acc[s][t][r], 0.f));
        }
    }
    __syncthreads();

    // phase 2: h3 = leaky(h2 @ Wlin + blin) + noise
    f32x4 acc2[2][2];
    #pragma unroll
    for (int s = 0; s < 2; s++)
        #pragma unroll
        for (int t = 0; t < 2; t++)
            acc2[s][t] = (f32x4){0.f, 0.f, 0.f, 0.f};

    #pragma unroll
    for (int kk = 0; kk < 2; kk++) {
        short8 ah[2];
        #pragma unroll
        for (int s = 0; s < 2; s++)
            ah[s] = *(const short8*)&h2s[(wm * 32 + s * 16 + mrow) * 72 + kk * 32 + quad * 8];
        #pragma unroll
        for (int s = 0; s < 2; s++)
            #pragma unroll
            for (int t = 0; t < 2; t++) {
                acc2[s][t] = __builtin_amdgcn_mfma_f32_16x16x32_bf16(ah[s], lhi[t][kk], acc2[s][t], 0, 0, 0);
                acc2[s][t] = __builtin_amdgcn_mfma_f32_16x16x32_bf16(ah[s], llo[t][kk], acc2[s][t], 0, 0, 0);
            }
    }

    #pragma unroll
    for (int s = 0; s < 2; s++) {
        int gmBase = m0 + wm * 32 + s * 16 + quad * 4;
        #pragma unroll
        for (int t = 0; t < 2; t++) {
            int gn = wn * 32 + t * 16 + mrow;
            float bb = blin[gn];
            #pragma unroll
            for (int r = 0; r < 4; r++) {
                int gm = gmBase + r;
                if (gm >= NN) continue;
                float v = acc2[s][t][r] + bb;
                v = (v > 0.f) ? v : 0.01f * v;
                v += noise[(long long)gm * 64 + gn];
                h3b[(long long)gm * 64 + gn] = f2bf(v);
            }
        }
    }
}

// ======== head layer-1 GEMM with integrated seed gather (bf16 h3, 2 MFMAs) ====
__global__ __launch_bounds__(256) void head1_gemm(
    const short* __restrict__ h3b, const int* __restrict__ seeds,
    const short* __restrict__ Bd_hi, const short* __restrict__ Bd_lo, const float* __restrict__ bd,
    const short* __restrict__ Bf_hi, const short* __restrict__ Bf_lo, const float* __restrict__ bfb,
    short* __restrict__ outd, short* __restrict__ outf)
{
    __shared__ short As[128 * 32];
    __shared__ short Bs_hi[64 * 32];
    __shared__ short Bs_lo[64 * 32];

    int z = blockIdx.z;
    int head = z >> 1, p = z & 1;
    const short* Bhi = (head ? Bf_hi : Bd_hi) + (long long)p * 256 * 64;
    const short* Blo = (head ? Bf_lo : Bd_lo) + (long long)p * 256 * 64;
    const float* bz = (head ? bfb : bd) + p * 256;
    short* Cc = (head ? outf : outd) + (long long)p * SS * 256;

    int m0 = blockIdx.y * 128;
    int n0 = blockIdx.x * 64;
    int tid = threadIdx.x;
    int lane = tid & 63;
    int w = tid >> 6;
    int wm = w >> 1, wn = w & 1;
    int mrow = lane & 15;
    int quad = lane >> 4;

    f32x4 acc[4][2];
    #pragma unroll
    for (int s = 0; s < 4; s++)
        #pragma unroll
        for (int t = 0; t < 2; t++)
            acc[s][t] = (f32x4){0.f, 0.f, 0.f, 0.f};

    #pragma unroll
    for (int k0 = 0; k0 < 64; k0 += 32) {
        #pragma unroll
        for (int i = 0; i < 2; i++) {
            int f = tid + i * 256;
            int m = f >> 2, q = f & 3;
            int node = seeds[m0 + m];
            *(short8*)&As[m * 32 + q * 8] = *(const short8*)&h3b[(long long)node * 64 + k0 + q * 8];
        }
        {
            int n = tid >> 2, q = tid & 3;
            long long boff = (long long)(n0 + n) * 64 + k0 + q * 8;
            *(short8*)&Bs_hi[n * 32 + q * 8] = *(const short8*)&Bhi[boff];
            *(short8*)&Bs_lo[n * 32 + q * 8] = *(const short8*)&Blo[boff];
        }
        __syncthreads();

        short8 ah[4], bh[2], bl[2];
        #pragma unroll
        for (int s = 0; s < 4; s++)
            ah[s] = *(const short8*)&As[(wm * 64 + s * 16 + mrow) * 32 + quad * 8];
        #pragma unroll
        for (int t = 0; t < 2; t++) {
            int soff = (wn * 32 + t * 16 + mrow) * 32 + quad * 8;
            bh[t] = *(const short8*)&Bs_hi[soff];
            bl[t] = *(const short8*)&Bs_lo[soff];
        }
        #pragma unroll
        for (int s = 0; s < 4; s++)
            #pragma unroll
            for (int t = 0; t < 2; t++) {
                acc[s][t] = __builtin_amdgcn_mfma_f32_16x16x32_bf16(ah[s], bh[t], acc[s][t], 0, 0, 0);
                acc[s][t] = __builtin_amdgcn_mfma_f32_16x16x32_bf16(ah[s], bl[t], acc[s][t], 0, 0, 0);
            }
        __syncthreads();
    }

    #pragma unroll
    for (int s = 0; s < 4; s++) {
        int gmBase = m0 + wm * 64 + s * 16 + quad * 4;
        #pragma unroll
        for (int t = 0; t < 2; t++) {
            int gn = n0 + wn * 32 + t * 16 + mrow;
            float bb = bz[gn];
            #pragma unroll
            for (int r = 0; r < 4; r++) {
                int gm = gmBase + r;
                float v = acc[s][t][r] + bb;
                v = (head == 1) ? fmaxf(v, 0.f) : ((v > 0.f) ? v : 0.01f * v);
                Cc[(long long)gm * 256 + gn] = f2bf(v);
            }
        }
    }
}

// ======== fused d-head: pred_missing = relu(leaky(d1@Wd2+bd2) @ Wd3 + bd3) ========
__global__ __launch_bounds__(256) void dhead_gemm(
    const short* __restrict__ d1b,                                  // [P][4096][256]
    const short* __restrict__ Bhi, const short* __restrict__ Blo,   // Wd2t [P][32][256]
    const float* __restrict__ bd2, const float* __restrict__ Wd3,
    const float* __restrict__ bd3, float* __restrict__ out)
{
    __shared__ short As[128 * 32];
    __shared__ short Bs_hi[64 * 32];
    __shared__ short Bs_lo[64 * 32];
    __shared__ float d2s[128][33];

    int p = blockIdx.z;
    const short* A = d1b + (long long)p * SS * 256;
    const short* Bh = Bhi + (long long)p * 32 * 256;
    const short* Bl = Blo + (long long)p * 32 * 256;

    int m0 = blockIdx.y * 128;
    int tid = threadIdx.x;
    int lane = tid & 63;
    int w = tid >> 6;
    int wm = w >> 1, wn = w & 1;
    int mrow = lane & 15;
    int quad = lane >> 4;

    f32x4 acc[4][2];
    #pragma unroll
    for (int s = 0; s < 4; s++)
        #pragma unroll
        for (int t = 0; t < 2; t++)
            acc[s][t] = (f32x4){0.f, 0.f, 0.f, 0.f};

    for (int k0 = 0; k0 < 256; k0 += 32) {
        #pragma unroll
        for (int i = 0; i < 2; i++) {
            int f = tid + i * 256;
            int m = f >> 2, q = f & 3;
            *(short8*)&As[m * 32 + q * 8] = *(const short8*)&A[(long long)(m0 + m) * 256 + k0 + q * 8];
        }
        {
            int n = tid >> 2, q = tid & 3;
            short8 bh = (short8)0, bl = (short8)0;
            if (n < 32) {
                long long boff = (long long)n * 256 + k0 + q * 8;
                bh = *(const short8*)&Bh[boff];
                bl = *(const short8*)&Bl[boff];
            }
            *(short8*)&Bs_hi[n * 32 + q * 8] = bh;
            *(short8*)&Bs_lo[n * 32 + q * 8] = bl;
        }
        __syncthreads();

        short8 ah[4], bh[2], bl[2];
        #pragma unroll
        for (int s = 0; s < 4; s++)
            ah[s] = *(const short8*)&As[(wm * 64 + s * 16 + mrow) * 32 + quad * 8];
        #pragma unroll
        for (int t = 0; t < 2; t++) {
            int soff = (wn * 32 + t * 16 + mrow) * 32 + quad * 8;
            bh[t] = *(const short8*)&Bs_hi[soff];
            bl[t] = *(const short8*)&Bs_lo[soff];
        }
        #pragma unroll
        for (int s = 0; s < 4; s++)
            #pragma unroll
            for (int t = 0; t < 2; t++) {
                acc[s][t] = __builtin_amdgcn_mfma_f32_16x16x32_bf16(ah[s], bh[t], acc[s][t], 0, 0, 0);
                acc[s][t] = __builtin_amdgcn_mfma_f32_16x16x32_bf16(ah[s], bl[t], acc[s][t], 0, 0, 0);
            }
        __syncthreads();
    }

    if (wn == 0) {
        #pragma unroll
        for (int s = 0; s < 4; s++) {
            int rowB = wm * 64 + s * 16 + quad * 4;
            #pragma unroll
            for (int t = 0; t < 2; t++) {
                int col = t * 16 + mrow;
                #pragma unroll
                for (int r = 0; r < 4; r++) {
                    float v = acc[s][t][r] + bd2[p * 32 + col];
                    d2s[rowB + r][col] = (v > 0.f) ? v : 0.01f * v;
                }
            }
        }
    }
    __syncthreads();

    if (tid < 128) {
        float sacc = bd3[p];
        #pragma unroll
        for (int k = 0; k < 32; k++) sacc += d2s[tid][k] * Wd3[p * 32 + k];
        out[p * SS + m0 + tid] = fmaxf(sacc, 0.f);
    }
}

// ================= MFMA GEMM, A = bf16 single plane (2 MFMAs), optional split-K =========
template <int ACT, bool OUTBF, int KSPLIT>
__global__ __launch_bounds__(256) void mfma_gemm_bfA(
    const short* __restrict__ A, int lda, long long sA,
    const short* __restrict__ Bhi, const short* __restrict__ Blo, long long sB,
    const float* __restrict__ bias, long long sBias,
    void* __restrict__ Cc, int ldc, long long sC,
    int M, int Nn, int K)
{
    __shared__ short As[128 * 32];
    __shared__ short Bs_hi[64 * 32];
    __shared__ short Bs_lo[64 * 32];

    int z = blockIdx.z;
    int p = z / KSPLIT, ks = z % KSPLIT;
    A += (long long)p * sA;
    Bhi += (long long)p * sB;
    Blo += (long long)p * sB;
    const float* bz = bias ? bias + (long long)p * sBias : nullptr;
    long long cbase = (long long)((KSPLIT > 1) ? z : p) * sC;

    int Kc = K / KSPLIT;
    int kbeg = ks * Kc;

    int m0 = blockIdx.y * 128;
    int n0 = blockIdx.x * 64;
    int tid = threadIdx.x;
    int lane = tid & 63;
    int w = tid >> 6;
    int wm = w >> 1, wn = w & 1;
    int mrow = lane & 15;
    int quad = lane >> 4;

    f32x4 acc[4][2];
    #pragma unroll
    for (int s = 0; s < 4; s++)
        #pragma unroll
        for (int t = 0; t < 2; t++)
            acc[s][t] = (f32x4){0.f, 0.f, 0.f, 0.f};

    for (int k0 = kbeg; k0 < kbeg + Kc; k0 += 32) {
        #pragma unroll
        for (int i = 0; i < 2; i++) {
            int f = tid + i * 256;
            int m = f >> 2, q = f & 3;
            int gm = m0 + m;
            short8 av = (short8)0;
            if (gm < M) av = *(const short8*)&A[(long long)gm * lda + k0 + q * 8];
            *(short8*)&As[m * 32 + q * 8] = av;
        }
        {
            int n = tid >> 2, q = tid & 3;
            int gn = n0 + n;
            short8 bh = (short8)0, bl = (short8)0;
            if (gn < Nn) {
                long long boff = (long long)gn * K + k0 + q * 8;
                bh = *(const short8*)&Bhi[boff];
                bl = *(const short8*)&Blo[boff];
            }
            *(short8*)&Bs_hi[n * 32 + q * 8] = bh;
            *(short8*)&Bs_lo[n * 32 + q * 8] = bl;
        }
        __syncthreads();

        short8 ah[4], bh[2], bl[2];
        #pragma unroll
        for (int s = 0; s < 4; s++)
            ah[s] = *(const short8*)&As[(wm * 64 + s * 16 + mrow) * 32 + quad * 8];
        #pragma unroll
        for (int t = 0; t < 2; t++) {
            int soff = (wn * 32 + t * 16 + mrow) * 32 + quad * 8;
            bh[t] = *(const short8*)&Bs_hi[soff];
            bl[t] = *(const short8*)&Bs_lo[soff];
        }
        #pragma unroll
        for (int s = 0; s < 4; s++)
            #pragma unroll
            for (int t = 0; t < 2; t++) {
                acc[s][t] = __builtin_amdgcn_mfma_f32_16x16x32_bf16(ah[s], bh[t], acc[s][t], 0, 0, 0);
                acc[s][t] = __builtin_amdgcn_mfma_f32_16x16x32_bf16(ah[s], bl[t], acc[s][t], 0, 0, 0);
            }
        __syncthreads();
    }

    #pragma unroll
    for (int s = 0; s < 4; s++) {
        int gmBase = m0 + wm * 64 + s * 16 + quad * 4;
        #pragma unroll
        for (int t = 0; t < 2; t++) {
            int gn = n0 + wn * 32 + t * 16 + mrow;
            if (gn >= Nn) continue;
            float bb = bz ? bz[gn] : 0.f;
            #pragma unroll
            for (int r = 0; r < 4; r++) {
                int gm = gmBase + r;
                if (gm >= M) continue;
                float v = acc[s][t][r] + bb;
                if (ACT == 1) v = fmaxf(v, 0.f);
                long long co = cbase + (long long)gm * ldc + gn;
                if (OUTBF) ((short*)Cc)[co] = f2bf(v);
                else ((float*)Cc)[co] = v;
            }
        }
    }
}

extern "C" void kernel_launch(void* const* d_in, const int* in_sizes, int n_in,
                              void* d_out, int out_size, void* d_ws, size_t ws_size,
                              hipStream_t stream) {
    const float* x    = (const float*)d_in[0];
    const int* edges  = (const int*)d_in[1];
    const int* seeds  = (const int*)d_in[2];
    const float* noise= (const float*)d_in[3];
    const float* V1   = (const float*)d_in[4];
    const float* C1   = (const float*)d_in[5];
    const float* V2   = (const float*)d_in[6];
    const float* C2   = (const float*)d_in[7];
    const float* Wlin = (const float*)d_in[8];
    const float* blin = (const float*)d_in[9];
    const float* Wd1 = (const float*)d_in[10]; const float* bd1 = (const float*)d_in[11];
    const float* Wd2 = (const float*)d_in[12]; const float* bd2 = (const float*)d_in[13];
    const float* Wd3 = (const float*)d_in[14]; const float* bd3 = (const float*)d_in[15];
    const float* Wf1 = (const float*)d_in[16]; const float* bf1 = (const float*)d_in[17];
    const float* Wf2 = (const float*)d_in[18]; const float* bf2 = (const float*)d_in[19];
    const float* Wf3 = (const float*)d_in[20]; const float* bf3 = (const float*)d_in[21];

    float* out = (float*)d_out;

    char* ws = (char*)d_ws;
    size_t off = 0;
    auto allocs = [&](size_t ns) {
        short* p = (short*)(ws + off);
        off += ((ns * 2 + 255) / 256) * 256;
        return p;
    };
    auto alloci = [&](size_t ni) {
        int* p = (int*)(ws + off);
        off += ((ni * 4 + 255) / 256) * 256;
        return p;
    };

    short* Wrt1_hi = allocs(16384);          short* Wrt1_lo = allocs(16384);
    short* Wrt2_hi = allocs(16384);          short* Wrt2_lo = allocs(16384);
    short* Wlint_hi = allocs(4096);          short* Wlint_lo = allocs(4096);
    short* Wd1t_hi = allocs(2 * 64 * 256);   short* Wd1t_lo = allocs(2 * 64 * 256);
    short* Wd2t_hi = allocs(2 * 256 * 32);   short* Wd2t_lo = allocs(2 * 256 * 32);
    short* Wf1t_hi = allocs(2 * 64 * 256);   short* Wf1t_lo = allocs(2 * 64 * 256);
    short* Wf2t_hi = allocs((size_t)2 * 256 * 2048);  short* Wf2t_lo = allocs((size_t)2 * 256 * 2048);
    short* Wf3t_hi = allocs((size_t)2 * 2048 * 320);  short* Wf3t_lo = allocs((size_t)2 * 2048 * 320);

    // CSR
    int* counts  = alloci(NSEG);
    int* excl    = alloci(NSEG);
    int* bsums   = alloci(2048);
    int* row_ptr = alloci(NSEG + 1);
    int* cursor  = alloci(NSEG);
    int* csr_src = alloci((size_t)RR * EE);

    short* xb  = allocs((size_t)NN * HH);        // bf16 copy of x
    short* agg = allocs((size_t)NSEG * HH);      // 51.2 MB; reused as fpart later
    short* h1  = allocs((size_t)NN * HH);        // bf16
    short* h3b = allocs((size_t)NN * HH);        // bf16 (post-noise)
    short* d1b = allocs((size_t)PP * SS * 256);  // bf16
    short* f1  = allocs((size_t)PP * SS * 256);  // bf16
    short* f2b = allocs((size_t)PP * SS * 2048); // bf16

    float* fpart = (float*)agg;                  // 4*2*4096*320*4 = 41.9 MB <= 51.2 MB

    // ---- prep (1 launch)
    PrepPtrs pp;
    pp.Wlin = Wlin; pp.Wd1 = Wd1; pp.Wd2 = Wd2; pp.Wf1 = Wf1; pp.Wf2 = Wf2; pp.Wf3 = Wf3;
    pp.Wlin_hi = Wlint_hi; pp.Wlin_lo = Wlint_lo;
    pp.Wd1_hi = Wd1t_hi;   pp.Wd1_lo = Wd1t_lo;
    pp.Wd2_hi = Wd2t_hi;   pp.Wd2_lo = Wd2t_lo;
    pp.Wf1_hi = Wf1t_hi;   pp.Wf1_lo = Wf1t_lo;
    pp.Wf2_hi = Wf2t_hi;   pp.Wf2_lo = Wf2t_lo;
    pp.Wf3_hi = Wf3t_hi;   pp.Wf3_lo = Wf3t_lo;
    pp.C1 = C1; pp.V1 = V1; pp.C2 = C2; pp.V2 = V2;
    pp.wr1_hi = Wrt1_hi; pp.wr1_lo = Wrt1_lo; pp.wr2_hi = Wrt2_hi; pp.wr2_lo = Wrt2_lo;
    pp.x = x; pp.xb = xb;
    prep_all<<<WR_BLK + TSP_BLK + XB_BLK, 256, 0, stream>>>(pp);

    // ---- CSR build
    hipMemsetAsync(counts, 0, (size_t)NSEG * 4, stream);
    int eb0 = (RR * EE + 255) / 256;                      // 4688
    count_kernel<<<eb0, 256, 0, stream>>>(edges, counts);
    int nb = (NSEG + 255) / 256;                          // 1563
    scan1<<<nb, 256, 0, stream>>>(counts, excl, bsums, NSEG);
    scan2<<<1, 256, 0, stream>>>(bsums, nb);
    scan3<<<nb, 256, 0, stream>>>(excl, bsums, row_ptr, cursor, NSEG, RR * EE);
    fill_csr<<<eb0 * FPART, 256, 0, stream>>>(edges, cursor, csr_src);

    int gb = (int)(((long long)NSEG * 8 + 255) / 256);    // 12500 blocks
    int MB64 = (NN + 63) / 64;                            // 1563

    // ---- layer 1
    gather_agg<<<gb, 256, 0, stream>>>(row_ptr, csr_src, xb, agg);
    combine1_kernel<<<MB64, 256, 0, stream>>>(agg, Wrt1_hi, Wrt1_lo, h1);

    // ---- layer 2 + linear (fused)
    gather_agg<<<gb, 256, 0, stream>>>(row_ptr, csr_src, h1, agg);
    combine2_linear<<<MB64, 256, 0, stream>>>(
        agg, Wrt2_hi, Wrt2_lo, Wlint_hi, Wlint_lo, blin, noise, h3b);

    // head layer 1: d1 (leaky) + f1 (relu), seeds gathered in-kernel
    head1_gemm<<<dim3(4, 32, 4), 256, 0, stream>>>(
        h3b, seeds, Wd1t_hi, Wd1t_lo, bd1, Wf1t_hi, Wf1t_lo, bf1, d1b, f1);

    // d-head fused: d2+d3 -> out[0 : P*S]
    dhead_gemm<<<dim3(1, 32, PP), 256, 0, stream>>>(
        d1b, Wd2t_hi, Wd2t_lo, bd2, Wd3, bd3, out);

    // f2 = relu(f1 @ Wf2 + bf2) -> bf16
    mfma_gemm_bfA<1, true, 1><<<dim3(32, 32, PP), 256, 0, stream>>>(
        f1, 256, (long long)SS * 256, Wf2t_hi, Wf2t_lo, (long long)2048 * 256, bf2, 2048,
        f2b, 2048, (long long)SS * 2048, SS, 2048, 256);
    // f3 partials: split-K=4
    mfma_gemm_bfA<0, false, 4><<<dim3(5, 32, PP * 4), 256, 0, stream>>>(
        f2b, 2048, (long long)SS * 2048, Wf3t_hi, Wf3t_lo, (long long)320 * 2048, nullptr, 0,
        fpart, 320, (long long)SS * 320, SS, 320, 2048);
    reduce_tanh<<<(PP * SS * 320 + 255) / 256, 256, 0, stream>>>(fpart, bf3, out + (size_t)PP * SS);
}